// Round 1
// baseline (406.567 us; speedup 1.0000x reference)
//
#include <hip/hip_runtime.h>

#define BATCH 64
#define SEQ 729
#define DIM 64
#define NT 12      // ceil(729/64)
#define STR 72     // LDS row stride in bf16 elems (pad 64 -> 72: 2-way conflicts only)

typedef __attribute__((ext_vector_type(8))) short bf16x8;
typedef __attribute__((ext_vector_type(4))) float f32x4;

__device__ __forceinline__ unsigned short f2bf(float f) {
    unsigned int u = __float_as_uint(f);
    u += 0x7fffu + ((u >> 16) & 1u);   // round-to-nearest-even
    return (unsigned short)(u >> 16);
}

// tanh(x) = 1 - 2/(exp2(2x*log2e)+1); exact -1 at x=-1e9, exact 0 at 0
__device__ __forceinline__ float fast_tanh(float x) {
    float e = __builtin_amdgcn_exp2f(x * 2.88539008177792681f);
    return 1.0f - 2.0f * __builtin_amdgcn_rcpf(e + 1.0f);
}

__global__ __launch_bounds__(256, 4) void attn_kernel(
    const float* __restrict__ Qg, const float* __restrict__ Kg,
    const float* __restrict__ Vg, const int* __restrict__ Mg,
    float* __restrict__ Og, float* __restrict__ Ag)
{
    __shared__ unsigned short Qs[64 * STR];   // Qs[q][d] bf16
    __shared__ unsigned short Ks[64 * STR];   // Ks[k][d] bf16
    __shared__ unsigned short Vs[64 * STR];   // Vs[d][k] bf16 (transposed!)
    __shared__ unsigned short Ps[64 * STR];   // Ps[q][k] bf16 (wave-private rows)

    const int tid = threadIdx.x;
    const int q0  = blockIdx.x * 64;
    const int b   = blockIdx.y;

    const float* Qb = Qg + (size_t)b * SEQ * DIM;
    const float* Kb = Kg + (size_t)b * SEQ * DIM;
    const float* Vb = Vg + (size_t)b * SEQ * DIM;
    const int*   Mb = Mg + (size_t)b * SEQ * SEQ;
    float* Ob = Og + (size_t)b * SEQ * DIM;
    float* Ab = Ag + (size_t)b * SEQ * SEQ;

    // ---- stage Q tile (64x64 fp32 -> bf16), once ----
    #pragma unroll
    for (int it = 0; it < 2; ++it) {
        int idx = tid + it * 256;            // 0..511
        int r = idx >> 3;                    // row 0..63
        int c = (idx & 7) * 8;               // col 0,8,...,56
        int gq = q0 + r;
        union { unsigned short u[8]; bf16x8 v; } t;
        if (gq < SEQ) {
            const float* src = Qb + gq * DIM + c;
            float4 x0 = *(const float4*)src;
            float4 x1 = *(const float4*)(src + 4);
            t.u[0]=f2bf(x0.x); t.u[1]=f2bf(x0.y); t.u[2]=f2bf(x0.z); t.u[3]=f2bf(x0.w);
            t.u[4]=f2bf(x1.x); t.u[5]=f2bf(x1.y); t.u[6]=f2bf(x1.z); t.u[7]=f2bf(x1.w);
        } else {
            #pragma unroll
            for (int j = 0; j < 8; ++j) t.u[j] = 0;
        }
        *(bf16x8*)&Qs[r * STR + c] = t.v;
    }

    const int w    = tid >> 6;
    const int lane = tid & 63;
    const int quad = lane >> 4;
    const int l15  = lane & 15;
    const int qrow = w * 16;                 // this wave's q-strip base (local)

    f32x4 oacc[4];
    #pragma unroll
    for (int dt = 0; dt < 4; ++dt) {
        oacc[dt][0] = 0.f; oacc[dt][1] = 0.f; oacc[dt][2] = 0.f; oacc[dt][3] = 0.f;
    }

    for (int kt = 0; kt < NT; ++kt) {
        const int k0 = kt * 64;

        // ---- prefetch mask into registers (hides latency behind barrier+MFMA) ----
        int mreg[4][4];
        #pragma unroll
        for (int nt2 = 0; nt2 < 4; ++nt2) {
            int gk = k0 + nt2 * 16 + l15;
            #pragma unroll
            for (int r = 0; r < 4; ++r) {
                int gq = q0 + qrow + quad * 4 + r;
                mreg[nt2][r] = (gq < SEQ && gk < SEQ) ? Mb[gq * SEQ + gk] : 0;
            }
        }

        __syncthreads();   // previous iter's readers of Ks/Vs are done

        // ---- stage K tile (row-major [k][d]) ----
        #pragma unroll
        for (int it = 0; it < 2; ++it) {
            int idx = tid + it * 256;
            int r = idx >> 3;
            int c = (idx & 7) * 8;
            int gk = k0 + r;
            union { unsigned short u[8]; bf16x8 v; } t;
            if (gk < SEQ) {
                const float* src = Kb + gk * DIM + c;
                float4 x0 = *(const float4*)src;
                float4 x1 = *(const float4*)(src + 4);
                t.u[0]=f2bf(x0.x); t.u[1]=f2bf(x0.y); t.u[2]=f2bf(x0.z); t.u[3]=f2bf(x0.w);
                t.u[4]=f2bf(x1.x); t.u[5]=f2bf(x1.y); t.u[6]=f2bf(x1.z); t.u[7]=f2bf(x1.w);
            } else {
                #pragma unroll
                for (int j = 0; j < 8; ++j) t.u[j] = 0;
            }
            *(bf16x8*)&Ks[r * STR + c] = t.v;
        }

        // ---- stage V tile transposed ([d][k]) ----
        {
            int d0  = (tid & 15) * 4;
            int kk0 = (tid >> 4) * 4;
            float rv[4][4];
            #pragma unroll
            for (int i = 0; i < 4; ++i) {
                int gk = k0 + kk0 + i;
                if (gk < SEQ) {
                    float4 x = *(const float4*)(Vb + gk * DIM + d0);
                    rv[i][0] = x.x; rv[i][1] = x.y; rv[i][2] = x.z; rv[i][3] = x.w;
                } else {
                    rv[i][0] = 0.f; rv[i][1] = 0.f; rv[i][2] = 0.f; rv[i][3] = 0.f;
                }
            }
            #pragma unroll
            for (int j = 0; j < 4; ++j) {
                unsigned long long pk =
                      (unsigned long long)f2bf(rv[0][j])
                    | ((unsigned long long)f2bf(rv[1][j]) << 16)
                    | ((unsigned long long)f2bf(rv[2][j]) << 32)
                    | ((unsigned long long)f2bf(rv[3][j]) << 48);
                *(unsigned long long*)&Vs[(d0 + j) * STR + kk0] = pk;
            }
        }

        __syncthreads();   // tiles visible

        // ---- QK^T: S[q][k], wave w owns q-strip [qrow, qrow+16) x all 64 k ----
        const bf16x8 aq0 = *(const bf16x8*)&Qs[(qrow + l15) * STR + quad * 8];
        const bf16x8 aq1 = *(const bf16x8*)&Qs[(qrow + l15) * STR + 32 + quad * 8];
        f32x4 sacc[4];
        #pragma unroll
        for (int nt2 = 0; nt2 < 4; ++nt2) {
            bf16x8 bk0 = *(const bf16x8*)&Ks[(nt2 * 16 + l15) * STR + quad * 8];
            bf16x8 bk1 = *(const bf16x8*)&Ks[(nt2 * 16 + l15) * STR + 32 + quad * 8];
            f32x4 c; c[0] = 0.f; c[1] = 0.f; c[2] = 0.f; c[3] = 0.f;
            c = __builtin_amdgcn_mfma_f32_16x16x32_bf16(aq0, bk0, c, 0, 0, 0);
            c = __builtin_amdgcn_mfma_f32_16x16x32_bf16(aq1, bk1, c, 0, 0, 0);
            sacc[nt2] = c;
        }

        // ---- scale, mask, tanh, zero-diag; store attention; write Ps ----
        #pragma unroll
        for (int nt2 = 0; nt2 < 4; ++nt2) {
            int gk = k0 + nt2 * 16 + l15;
            #pragma unroll
            for (int r = 0; r < 4; ++r) {
                int qloc = qrow + quad * 4 + r;
                int gq = q0 + qloc;
                float sv = sacc[nt2][r] * 0.125f;     // 1/sqrt(64)
                bool msk = (mreg[nt2][r] == 0);
                float x = msk ? -1e9f : sv;
                float p = fast_tanh(x);
                if (msk) p = -1.0f;                   // exact, matches tanh(-1e9)
                if (gq == gk) p = 0.0f;               // ignore_diag
                bool inb = (gq < SEQ) && (gk < SEQ);
                if (!inb) p = 0.0f;                   // padding contributes nothing
                if (inb) Ab[gq * SEQ + gk] = p;       // coalesced: 16 lanes = 64B
                Ps[qloc * STR + nt2 * 16 + l15] = f2bf(p);
            }
        }
        // Ps rows [qrow, qrow+16) are written and read by THIS wave only -> no barrier

        // ---- PV: out[q][d] += P[q][k] * V[k][d] ----
        const bf16x8 ap0 = *(const bf16x8*)&Ps[(qrow + l15) * STR + quad * 8];
        const bf16x8 ap1 = *(const bf16x8*)&Ps[(qrow + l15) * STR + 32 + quad * 8];
        #pragma unroll
        for (int dt = 0; dt < 4; ++dt) {
            bf16x8 bv0 = *(const bf16x8*)&Vs[(dt * 16 + l15) * STR + quad * 8];
            bf16x8 bv1 = *(const bf16x8*)&Vs[(dt * 16 + l15) * STR + 32 + quad * 8];
            oacc[dt] = __builtin_amdgcn_mfma_f32_16x16x32_bf16(ap0, bv0, oacc[dt], 0, 0, 0);
            oacc[dt] = __builtin_amdgcn_mfma_f32_16x16x32_bf16(ap1, bv1, oacc[dt], 0, 0, 0);
        }
    }

    // ---- epilogue: write out[q][d] ----
    #pragma unroll
    for (int dt = 0; dt < 4; ++dt) {
        #pragma unroll
        for (int r = 0; r < 4; ++r) {
            int gq = q0 + qrow + quad * 4 + r;
            if (gq < SEQ) Ob[gq * DIM + dt * 16 + l15] = oacc[dt][r];
        }
    }
}

extern "C" void kernel_launch(void* const* d_in, const int* in_sizes, int n_in,
                              void* d_out, int out_size, void* d_ws, size_t ws_size,
                              hipStream_t stream) {
    const float* Q = (const float*)d_in[0];
    const float* K = (const float*)d_in[1];
    const float* V = (const float*)d_in[2];
    const int*   M = (const int*)d_in[3];
    float* Out  = (float*)d_out;
    float* Attn = Out + (size_t)BATCH * SEQ * DIM;   // tuple order: (out, attention)
    dim3 grid(NT, BATCH);
    attn_kernel<<<grid, 256, 0, stream>>>(Q, K, V, M, Out, Attn);
}